// Round 11
// baseline (628.691 us; speedup 1.0000x reference)
//
#include <hip/hip_runtime.h>

typedef unsigned int uint32;
typedef __bf16 bf16x8 __attribute__((ext_vector_type(8)));
typedef __bf16 bf16x4 __attribute__((ext_vector_type(4)));
typedef float f32x4 __attribute__((ext_vector_type(4)));

constexpr int N_C = 100000, N_T = 5000, E_EDGES = 2000000;
constexpr int D_C = 1024, D_T = 1280, H = 64, H2 = 32, NL = 3;
constexpr int PJC = (N_C + 63) / 64;     // 1563 proj blocks (64 rows/block)
constexpr int PJT = (N_T + 63) / 64;     // 79
constexpr int NBC64 = (N_C + 63) / 64;   // 1563 layerC blocks

// ---- CSR build (two-level counting sort) ----
constexpr int CCH = 800;                  // chunks per graph (4x for occupancy)
constexpr int CHE = E_EDGES / CCH;        // 2500 edges per chunk (exact)
constexpr int SH_T = 4,  FB_T = 16;       // target: bucket = dst>>4, 16 fine bins
constexpr int SH_C = 8,  FB_C = 256;      // compound: bucket = dst>>8, 256 fine bins
constexpr int NB_T_B = (N_T + FB_T - 1) / FB_T;   // 313 buckets
constexpr int NB_C_B = (N_C + FB_C - 1) / FB_C;   // 391 buckets
constexpr int NB_TOT = NB_T_B + NB_C_B;           // 704
constexpr int PB_T = 17; constexpr uint32 PM_T = 0x1FFFFu;
constexpr int PB_C = 13; constexpr uint32 PM_C = 0x1FFFu;

__device__ inline unsigned short f2bf(float f) {
  uint32 u = __float_as_uint(f);
  u += 0x7fffu + ((u >> 16) & 1u);          // round-to-nearest-even
  return (unsigned short)(u >> 16);
}

// ---------------- prep: fragment-major weight packs + small transposes + zero totals
__global__ __launch_bounds__(256) void prep_kernel(
    const float* __restrict__ Wc, const float* __restrict__ Wt,
    const float* __restrict__ Wl, const float* __restrict__ Wr,
    __bf16* __restrict__ WfC, __bf16* __restrict__ WfT, __bf16* __restrict__ WsT,
    int* __restrict__ T)
{
  int t = blockIdx.x * 256 + threadIdx.x;
  const int Z = NB_TOT;
  const int A = D_C * 64;
  const int B = D_T * 64;
  const int S = 6 * 64 * 64;
  if (t < Z) { T[t] = 0; return; }
  t -= Z;
  if (t < A) {
    int j = t & 7, l = (t >> 3) & 63, frag = t >> 9;
    int k0 = (frag >> 2) * 32, fn = frag & 3;
    int lm = l & 15, lk = l >> 4;
    WfC[t] = (__bf16)Wc[(size_t)(k0 + lk * 8 + j) * 64 + fn * 16 + lm];
    return;
  }
  t -= A;
  if (t < B) {
    int j = t & 7, l = (t >> 3) & 63, frag = t >> 9;
    int k0 = (frag >> 2) * 32, fn = frag & 3;
    int lm = l & 15, lk = l >> 4;
    WfT[t] = (__bf16)Wt[(size_t)(k0 + lk * 8 + j) * 64 + fn * 16 + lm];
    return;
  }
  t -= B;
  if (t < S) {
    int i = t >> 12;
    int r = t & 4095; int n = r & 63, k = r >> 6;
    const float* src = (i < 3) ? (Wl + (size_t)i * 4096) : (Wr + (size_t)(i - 3) * 4096);
    WsT[(size_t)i * 4096 + (size_t)n * 64 + k] = (__bf16)src[(size_t)k * 64 + n];
  }
}

// ---------------- MFMA projection: LDS-staged contiguous streaming (R9 body)
template<int K>
__device__ __forceinline__ void projLDS_body(
    const float* __restrict__ x, const __bf16* __restrict__ Wf,
    const float* __restrict__ b, float* __restrict__ y,
    unsigned short* __restrict__ yh, int n, int bidx)
{
  constexpr int NT = K / 128;
  constexpr int ST = 152;                  // LDS row stride in bf16 (19.5 KB total)
  __shared__ __align__(16) __bf16 sA[64 * ST];

  int t = threadIdx.x;
  int w = t >> 6, l = t & 63;
  int lm = l & 15, lk = l >> 4;
  int bbase = bidx * 64;
  int rowbase = bbase + w * 16;

  f32x4 acc[4] = {{0,0,0,0},{0,0,0,0},{0,0,0,0},{0,0,0,0}};

  int srow = t >> 5;
  int sc4  = t & 31;

  for (int tile = 0; tile < NT; ++tile) {
    if (tile) __syncthreads();
    float4 g[8];
#pragma unroll
    for (int r = 0; r < 8; ++r) {
      int row = srow + r * 8;
      int gr = bbase + row; if (gr >= n) gr = n - 1;
      g[r] = *(const float4*)(x + (size_t)gr * K + tile * 128 + sc4 * 4);
    }
#pragma unroll
    for (int r = 0; r < 8; ++r) {
      int row = srow + r * 8;
      bf16x4 v;
      v[0] = (__bf16)g[r].x; v[1] = (__bf16)g[r].y;
      v[2] = (__bf16)g[r].z; v[3] = (__bf16)g[r].w;
      *(bf16x4*)(sA + (size_t)row * ST + sc4 * 4) = v;
    }
    __syncthreads();

#pragma unroll
    for (int kk = 0; kk < 4; ++kk) {
      bf16x8 a0 = *(const bf16x8*)(sA + (size_t)(w * 16 + lm) * ST + kk * 32 + lk * 8);
#pragma unroll
      for (int fn = 0; fn < 4; ++fn) {
        bf16x8 bv = *(const bf16x8*)(Wf + ((size_t)(tile * 4 + kk) * 4 + fn) * 512 + l * 8);
        acc[fn] = __builtin_amdgcn_mfma_f32_16x16x32_bf16(a0, bv, acc[fn], 0, 0, 0);
      }
    }
  }

#pragma unroll
  for (int fn = 0; fn < 4; ++fn) {
    int col = fn * 16 + lm;
    float bb = b[col];
#pragma unroll
    for (int reg = 0; reg < 4; ++reg) {
      int row = rowbase + lk * 4 + reg;
      if (row < n) {
        float o = fmaxf(acc[fn][reg] + bb, 0.f);
        y[(size_t)row * 64 + col] = o;
        yh[(size_t)row * 64 + col] = f2bf(o);
      }
    }
  }
}

__global__ __launch_bounds__(256) void proj_kernel(
    const float* __restrict__ x_comp, const __bf16* __restrict__ WfC,
    const float* __restrict__ bc, float* __restrict__ xc, unsigned short* __restrict__ xch,
    const float* __restrict__ x_tgt, const __bf16* __restrict__ WfT,
    const float* __restrict__ bt, float* __restrict__ xt, unsigned short* __restrict__ xth)
{
  if (blockIdx.x < PJC) projLDS_body<D_C>(x_comp, WfC, bc, xc, xch, N_C, blockIdx.x);
  else                  projLDS_body<D_T>(x_tgt, WfT, bt, xt, xth, N_T, blockIdx.x - PJC);
}

// ---------------- csr1: per-chunk coarse-bucket histograms (LDS), 1600 blocks
__global__ __launch_bounds__(256) void csr1_kernel(
    const int* __restrict__ dst_ct, const int* __restrict__ dst_tc,
    int* __restrict__ h1, int* __restrict__ T)
{
  __shared__ int hist[NB_C_B];
  int graph = (blockIdx.x >= CCH) ? 1 : 0;
  int chunk = graph ? (blockIdx.x - CCH) : blockIdx.x;
  const int* dst = graph ? dst_tc : dst_ct;
  int NB = graph ? NB_C_B : NB_T_B;
  int SH = graph ? SH_C : SH_T;
  for (int i = threadIdx.x; i < NB; i += 256) hist[i] = 0;
  __syncthreads();
  int e0 = chunk * CHE;
  for (int i = threadIdx.x; i < CHE; i += 256)
    atomicAdd(&hist[dst[e0 + i] >> SH], 1);
  __syncthreads();
  int* h1g = h1 + (graph ? (size_t)NB_T_B * CCH : 0);
  int* Tg  = T + (graph ? NB_T_B : 0);
  for (int i = threadIdx.x; i < NB; i += 256) {
    int v = hist[i];
    h1g[(size_t)i * CCH + chunk] = v;
    if (v) atomicAdd(&Tg[i], v);       // fire-and-forget
  }
}

// ---------------- csr2: per-bucket bases + chunk-prefix of h1 row (800, 4/thread)
__global__ __launch_bounds__(256) void csr2_kernel(
    const int* __restrict__ h1, const int* __restrict__ T, int* __restrict__ b1)
{
  __shared__ int sh[256];
  __shared__ int loc2[512];
  int b = blockIdx.x;
  int graph = (b >= NB_T_B) ? 1 : 0;
  int nb = graph ? NB_C_B : NB_T_B;
  int base = graph ? NB_T_B : 0;
  int bl = b - base;
  int tid = threadIdx.x;
  // exclusive scan of this graph's bucket totals (<=391, 2 per thread)
  int v0 = (2 * tid     < nb) ? T[base + 2 * tid]     : 0;
  int v1 = (2 * tid + 1 < nb) ? T[base + 2 * tid + 1] : 0;
  int t = v0 + v1;
  sh[tid] = t;
  __syncthreads();
  for (int off = 1; off < 256; off <<= 1) {
    int xv = (tid >= off) ? sh[tid - off] : 0;
    __syncthreads(); sh[tid] += xv; __syncthreads();
  }
  int excl = sh[tid] - t;
  loc2[2 * tid] = excl;
  loc2[2 * tid + 1] = excl + v0;
  __syncthreads();
  int B = loc2[bl];
  // exclusive chunk-prefix of own h1 row (CCH=800 entries, 4 per thread)
  const int* row = h1 + (graph ? (size_t)NB_T_B * CCH : 0) + (size_t)bl * CCH;
  int c0 = tid * 4;
  int h0 = (c0 + 0 < CCH) ? row[c0 + 0] : 0;
  int h1v = (c0 + 1 < CCH) ? row[c0 + 1] : 0;
  int h2 = (c0 + 2 < CCH) ? row[c0 + 2] : 0;
  int h3 = (c0 + 3 < CCH) ? row[c0 + 3] : 0;
  int ts = h0 + h1v + h2 + h3;
  __syncthreads();
  sh[tid] = ts;
  __syncthreads();
  for (int off = 1; off < 256; off <<= 1) {
    int xv = (tid >= off) ? sh[tid - off] : 0;
    __syncthreads(); sh[tid] += xv; __syncthreads();
  }
  int e2 = sh[tid] - ts;
  int* b1g = b1 + (graph ? (size_t)NB_T_B * CCH : 0) + (size_t)bl * CCH;
  if (c0 + 0 < CCH) b1g[c0 + 0] = B + e2;
  if (c0 + 1 < CCH) b1g[c0 + 1] = B + e2 + h0;
  if (c0 + 2 < CCH) b1g[c0 + 2] = B + e2 + h0 + h1v;
  if (c0 + 3 < CCH) b1g[c0 + 3] = B + e2 + h0 + h1v + h2;
}

// ---------------- csr3: scatter edges into bucket-major temp (packed), 1600 blocks
__global__ __launch_bounds__(256) void csr3_kernel(
    const int* __restrict__ src_ct, const int* __restrict__ dst_ct,
    const int* __restrict__ src_tc, const int* __restrict__ dst_tc,
    const int* __restrict__ b1, uint32* __restrict__ packT_t, uint32* __restrict__ packT_c)
{
  __shared__ int cur[NB_C_B];
  int graph = (blockIdx.x >= CCH) ? 1 : 0;
  int chunk = graph ? (blockIdx.x - CCH) : blockIdx.x;
  const int* dst = graph ? dst_tc : dst_ct;
  const int* src = graph ? src_tc : src_ct;
  uint32* packT = graph ? packT_c : packT_t;
  int NB = graph ? NB_C_B : NB_T_B;
  int SH = graph ? SH_C : SH_T;
  int SB = graph ? PB_C : PB_T;
  const int* b1g = b1 + (graph ? (size_t)NB_T_B * CCH : 0);
  for (int i = threadIdx.x; i < NB; i += 256) cur[i] = b1g[(size_t)i * CCH + chunk];
  __syncthreads();
  int e0 = chunk * CHE;
  for (int i = threadIdx.x; i < CHE; i += 256) {
    int d = dst[e0 + i], s = src[e0 + i];
    int p = atomicAdd(&cur[d >> SH], 1);   // LDS atomic
    packT[p] = ((uint32)d << SB) | (uint32)s;
  }
}

// ---------------- csr4: per-bucket fine counting sort -> rowptr + col (plain src)
__global__ __launch_bounds__(256) void csr4_kernel(
    const int* __restrict__ b1, const uint32* __restrict__ packT_t,
    const uint32* __restrict__ packT_c,
    int* __restrict__ rowptr_t, int* __restrict__ col_ct,
    int* __restrict__ rowptr_c, int* __restrict__ col_tc)
{
  __shared__ int hist[FB_C];
  __shared__ int exc[256];
  int b = blockIdx.x;
  int graph = (b >= NB_T_B) ? 1 : 0;
  int bl = graph ? (b - NB_T_B) : b;
  int nb = graph ? NB_C_B : NB_T_B;
  int FB = graph ? FB_C : FB_T;
  int SB = graph ? PB_C : PB_T;
  uint32 SM = graph ? PM_C : PM_T;
  uint32 FMM = (uint32)(FB - 1);
  int N  = graph ? N_C : N_T;
  const uint32* packT = graph ? packT_c : packT_t;
  int* rowptr = graph ? rowptr_c : rowptr_t;
  int* col    = graph ? col_tc : col_ct;
  const int* b1g = b1 + (graph ? (size_t)NB_T_B * CCH : 0);
  int seg0 = b1g[(size_t)bl * CCH];
  int seg1 = (bl + 1 < nb) ? b1g[(size_t)(bl + 1) * CCH] : E_EDGES;
  int tid = threadIdx.x;
  if (tid < FB) hist[tid] = 0;
  __syncthreads();
  for (int i = seg0 + tid; i < seg1; i += 256)
    atomicAdd(&hist[(packT[i] >> SB) & FMM], 1);
  __syncthreads();
  int hv = (tid < FB) ? hist[tid] : 0;
  exc[tid] = hv;
  __syncthreads();
  for (int off = 1; off < 256; off <<= 1) {
    int xv = (tid >= off) ? exc[tid - off] : 0;
    __syncthreads(); exc[tid] += xv; __syncthreads();
  }
  int excl = exc[tid] - hv;
  __syncthreads();
  if (tid < FB) {
    int gbin = bl * FB + tid;
    if (gbin <= N) rowptr[gbin] = seg0 + excl;
    hist[tid] = seg0 + excl;
  }
  __syncthreads();
  for (int i = seg0 + tid; i < seg1; i += 256) {
    uint32 pk = packT[i];
    int p = atomicAdd(&hist[(pk >> SB) & FMM], 1);
    col[p] = (int)(pk & SM);                      // plain src index
  }
}

// ---------------- fused layer node: blocks [0,N_T) target SAGE; [N_T,+NBC64) compound
__global__ __launch_bounds__(256) void layer_kernel(
    const unsigned short* __restrict__ xch_a, const float* __restrict__ xt_a,
    const int* __restrict__ rowptr_t, const int* __restrict__ col_ct,
    const float* __restrict__ Wl_t, const float* __restrict__ bl_t, const float* __restrict__ Wr_t,
    float* __restrict__ xt_n, unsigned short* __restrict__ xth_n,
    const unsigned short* __restrict__ xth_a, const int* __restrict__ rowptr_c,
    const int* __restrict__ col_tc,
    const __bf16* __restrict__ WlT, const __bf16* __restrict__ WrT,
    const float* __restrict__ bl_c, const float* __restrict__ xc_a,
    float* __restrict__ xc_n, unsigned short* __restrict__ xch_n)
{
  __shared__ __align__(16) uint32 smem_u[64 * 36];   // 9.2 KB; target side aliases front
  float (*part)[64]  = (float(*)[64])smem_u;
  float (*opart)[64] = (float(*)[64])(smem_u + 256);

  int l = threadIdx.x & 63, w = threadIdx.x >> 6;
  int d = l & 31, half = l >> 5;

  if (blockIdx.x < N_T) {
    // -------- target-side SAGE (masked batch gather, R10 body)
    int r = blockIdx.x;
    int start = rowptr_t[r], end = rowptr_t[r + 1];
    int deg = end - start;
    int quarter = (deg + 3) >> 2;
    int js = start + w * quarter;
    int je = js + quarter; if (je > end) je = end;
    const uint32* xp = (const uint32*)xch_a;
    float a0 = 0.f, a1 = 0.f;
    int j0 = js + half;
    for (int j = j0; j < je; j += 16) {
      int idx[8]; uint32 vv[8];
#pragma unroll
      for (int k = 0; k < 8; ++k) {
        int jj = j + 2 * k;
        idx[k] = col_ct[(jj < je) ? jj : j];
      }
#pragma unroll
      for (int k = 0; k < 8; ++k) vv[k] = xp[(size_t)idx[k] * 32 + d];
#pragma unroll
      for (int k = 0; k < 8; ++k) {
        bool m = (j + 2 * k) < je;
        a0 += m ? __uint_as_float(vv[k] << 16) : 0.f;
        a1 += m ? __uint_as_float(vv[k] & 0xffff0000u) : 0.f;
      }
    }
    a0 += __shfl_xor(a0, 32, 64);
    a1 += __shfl_xor(a1, 32, 64);
    if (half == 0) *(float2*)&part[w][2 * d] = make_float2(a0, a1);
    __syncthreads();
    float m = (part[0][l] + part[1][l] + part[2][l] + part[3][l])
              * ((deg > 0) ? (1.0f / (float)deg) : 0.f);
    float xv = xt_a[(size_t)r * 64 + l];
    float o = 0.f;
    int k0 = w * 16;
#pragma unroll
    for (int kk = 0; kk < 16; ++kk) {
      int k = k0 + kk;
      float mk = __uint_as_float(__builtin_amdgcn_readlane(__float_as_uint(m), k));
      float xk = __uint_as_float(__builtin_amdgcn_readlane(__float_as_uint(xv), k));
      o = fmaf(mk, Wl_t[k * 64 + l], o);
      o = fmaf(xk, Wr_t[k * 64 + l], o);
    }
    opart[w][l] = o;
    __syncthreads();
    if (w == 0) {
      float oo = opart[0][l] + opart[1][l] + opart[2][l] + opart[3][l] + bl_t[l];
      float res = fmaxf(oo, 0.f) + xv;
      xt_n[(size_t)r * 64 + l] = res;
      xth_n[(size_t)r * 64 + l] = f2bf(res);
    }
    return;
  }

  // -------- compound side (64 rows/block, 16/wave; masked batch gather, R10 body)
  int bbase = (blockIdx.x - N_T) * 64;

  int rp_idx = bbase + w * 16 + ((l <= 16) ? l : 16);
  if (rp_idx > N_C) rp_idx = N_C;
  int rpl = rowptr_c[rp_idx];
  const uint32* xp = (const uint32*)xth_a;

#pragma unroll 1
  for (int t = 0; t < 8; ++t) {
    int s = __shfl(rpl, 2 * t + half, 64);
    int e = __shfl(rpl, 2 * t + half + 1, 64);
    float a0 = 0.f, a1 = 0.f;
    int n = e - s;
    for (int j = 0; j < n; j += 8) {
      int idx[8]; uint32 vv[8];
#pragma unroll
      for (int k = 0; k < 8; ++k) {
        int jj = s + j + k;
        idx[k] = col_tc[(jj < e) ? jj : s];
      }
#pragma unroll
      for (int k = 0; k < 8; ++k) vv[k] = xp[(size_t)idx[k] * 32 + d];
#pragma unroll
      for (int k = 0; k < 8; ++k) {
        bool m = (j + k) < n;
        a0 += m ? __uint_as_float(vv[k] << 16) : 0.f;
        a1 += m ? __uint_as_float(vv[k] & 0xffff0000u) : 0.f;
      }
    }
    float inv = (n > 0) ? (1.0f / (float)n) : 0.f;
    uint32 packed = (uint32)f2bf(a0 * inv) | ((uint32)f2bf(a1 * inv) << 16);
    smem_u[(size_t)(w * 16 + 2 * t + half) * 36 + d] = packed;
  }
  __syncthreads();

  int lm = l & 15, lk = l >> 4;
  int base = bbase + w * 16;
  int r0 = base + lm; if (r0 >= N_C) r0 = N_C - 1;
  const unsigned short* x0 = xch_a + (size_t)r0 * 64 + lk * 8;
  const __bf16* wl = WlT + (size_t)lm * 64 + lk * 8;
  const __bf16* wr = WrT + (size_t)lm * 64 + lk * 8;

  f32x4 acc[4] = {{0,0,0,0},{0,0,0,0},{0,0,0,0},{0,0,0,0}};

#pragma unroll
  for (int ks = 0; ks < 64; ks += 32) {
    bf16x8 am0 = *(const bf16x8*)&smem_u[(size_t)(w * 16 + lm) * 36 + lk * 4 + (ks >> 1)];
    bf16x8 ax0 = *(const bf16x8*)(x0 + ks);
#pragma unroll
    for (int fn = 0; fn < 4; ++fn) {
      bf16x8 bl_v = *(const bf16x8*)(wl + (size_t)fn * 16 * 64 + ks);
      bf16x8 br_v = *(const bf16x8*)(wr + (size_t)fn * 16 * 64 + ks);
      acc[fn] = __builtin_amdgcn_mfma_f32_16x16x32_bf16(am0, bl_v, acc[fn], 0, 0, 0);
      acc[fn] = __builtin_amdgcn_mfma_f32_16x16x32_bf16(ax0, br_v, acc[fn], 0, 0, 0);
    }
  }

#pragma unroll
  for (int fn = 0; fn < 4; ++fn) {
    int col = fn * 16 + lm;
    float bb = bl_c[col];
#pragma unroll
    for (int reg = 0; reg < 4; ++reg) {
      int row = base + lk * 4 + reg;
      if (row < N_C) {
        float xv = xc_a[(size_t)row * 64 + col];
        float o = fmaxf(acc[fn][reg] + bb, 0.f) + xv;
        xc_n[(size_t)row * 64 + col] = o;
        xch_n[(size_t)row * 64 + col] = f2bf(o);
      }
    }
  }
}

// ---------------- head: out[r] = relu(xc[r] @ Wo1 + bo1) @ Wo2 + bo2
__global__ __launch_bounds__(256) void head_kernel(
    const float* __restrict__ xc, const float* __restrict__ Wo1,
    const float* __restrict__ bo1, const float* __restrict__ Wo2,
    const float* __restrict__ bo2, float* __restrict__ out, int n)
{
  int lane = threadIdx.x & 63;
  int wid = blockIdx.x * (blockDim.x >> 6) + (threadIdx.x >> 6);
  if (wid >= n) return;
  float xv = xc[(size_t)wid * 64 + lane];
  float h = (lane < H2) ? bo1[lane] : 0.f;
  const float* wcol = Wo1 + ((lane < H2) ? lane : 0);
#pragma unroll 8
  for (int k = 0; k < 64; ++k) {
    float xk = __uint_as_float(__builtin_amdgcn_readlane(__float_as_uint(xv), k));
    h = fmaf(xk, wcol[k * H2], h);
  }
  float v = (lane < H2) ? fmaxf(h, 0.f) * Wo2[lane] : 0.f;
#pragma unroll
  for (int off = 32; off > 0; off >>= 1) v += __shfl_down(v, off, 64);
  if (lane == 0) out[wid] = v + bo2[0];
}

extern "C" void kernel_launch(void* const* d_in, const int* in_sizes, int n_in,
                              void* d_out, int out_size, void* d_ws, size_t ws_size,
                              hipStream_t stream)
{
  const float* x_comp = (const float*)d_in[0];
  const float* x_tgt  = (const float*)d_in[1];
  const int*   src_ct = (const int*)d_in[2];
  const int*   dst_ct = (const int*)d_in[3];
  const int*   src_tc = (const int*)d_in[4];
  const int*   dst_tc = (const int*)d_in[5];
  const float* Wc    = (const float*)d_in[6];
  const float* bc    = (const float*)d_in[7];
  const float* Wt    = (const float*)d_in[8];
  const float* bt    = (const float*)d_in[9];
  const float* Wl_ct = (const float*)d_in[10];
  const float* bl_ct = (const float*)d_in[11];
  const float* Wr_ct = (const float*)d_in[12];
  const float* Wl_tc = (const float*)d_in[13];
  const float* bl_tc = (const float*)d_in[14];
  const float* Wr_tc = (const float*)d_in[15];
  const float* Wo1   = (const float*)d_in[16];
  const float* bo1   = (const float*)d_in[17];
  const float* Wo2   = (const float*)d_in[18];
  const float* bo2   = (const float*)d_in[19];
  float* out = (float*)d_out;

  char* p = (char*)d_ws;
  auto alloc = [&](size_t bytes) {
    char* q = p;
    p += (bytes + 255) & ~(size_t)255;
    return q;
  };
  float* xc   = (float*)alloc((size_t)N_C * H * 4);
  float* xt   = (float*)alloc((size_t)N_T * H * 4);
  float* xc_b = (float*)alloc((size_t)N_C * H * 4);
  float* xt_b = (float*)alloc((size_t)N_T * H * 4);
  unsigned short* xch   = (unsigned short*)alloc((size_t)N_C * H * 2);
  unsigned short* xth   = (unsigned short*)alloc((size_t)N_T * H * 2);
  unsigned short* xch_b = (unsigned short*)alloc((size_t)N_C * H * 2);
  unsigned short* xth_b = (unsigned short*)alloc((size_t)N_T * H * 2);
  __bf16* WfC = (__bf16*)alloc((size_t)D_C * H * 2);
  __bf16* WfT = (__bf16*)alloc((size_t)D_T * H * 2);
  __bf16* WsT = (__bf16*)alloc((size_t)6 * H * H * 2);
  int*    h1        = (int*)alloc((size_t)NB_TOT * CCH * 4);
  int*    b1        = (int*)alloc((size_t)NB_TOT * CCH * 4);
  int*    T         = (int*)alloc((size_t)NB_TOT * 4);
  uint32* packT_t   = (uint32*)alloc((size_t)E_EDGES * 4);
  uint32* packT_c   = (uint32*)alloc((size_t)E_EDGES * 4);
  int*    rowptr_t  = (int*)alloc((size_t)(N_T + 1) * 4);
  int*    rowptr_c  = (int*)alloc((size_t)(N_C + 1) * 4);
  int*    col_ct    = (int*)alloc((size_t)E_EDGES * 4);
  int*    col_tc    = (int*)alloc((size_t)E_EDGES * 4);

  // node 1: weight prep (fragment-major packs) + zero bucket totals
  const int PREP_TOTAL = NB_TOT + D_C * 64 + D_T * 64 + 6 * 4096;
  prep_kernel<<<dim3((PREP_TOTAL + 255) / 256), dim3(256), 0, stream>>>(
      Wc, Wt, Wl_tc, Wr_tc, WfC, WfT, WsT, T);

  // node 2: both dense input projections (LDS-staged contiguous streaming)
  proj_kernel<<<dim3(PJC + PJT), dim3(256), 0, stream>>>(
      x_comp, WfC, bc, xc, xch, x_tgt, WfT, bt, xt, xth);

  // nodes 3-6: CSR build (two-level counting sort, 800 chunks/graph)
  csr1_kernel<<<dim3(2 * CCH), dim3(256), 0, stream>>>(dst_ct, dst_tc, h1, T);
  csr2_kernel<<<dim3(NB_TOT), dim3(256), 0, stream>>>(h1, T, b1);
  csr3_kernel<<<dim3(2 * CCH), dim3(256), 0, stream>>>(
      src_ct, dst_ct, src_tc, dst_tc, b1, packT_t, packT_c);
  csr4_kernel<<<dim3(NB_TOT), dim3(256), 0, stream>>>(
      b1, packT_t, packT_c, rowptr_t, col_ct, rowptr_c, col_tc);

  // nodes 7-9: one fused node per layer (T blocks + C blocks co-scheduled)
  float* xc_a = xc; float* xt_a = xt;
  float* xc_n = xc_b; float* xt_n = xt_b;
  unsigned short* xch_a = xch; unsigned short* xth_a = xth;
  unsigned short* xch_n = xch_b; unsigned short* xth_n = xth_b;
  for (int l = 0; l < NL; ++l) {
    layer_kernel<<<dim3(N_T + NBC64), dim3(256), 0, stream>>>(
        xch_a, xt_a, rowptr_t, col_ct,
        Wl_ct + (size_t)l * H * H, bl_ct + (size_t)l * H, Wr_ct + (size_t)l * H * H,
        xt_n, xth_n,
        xth_a, rowptr_c, col_tc,
        WsT + (size_t)l * H * H, WsT + (size_t)(3 + l) * H * H,
        bl_tc + (size_t)l * H, xc_a, xc_n, xch_n);
    float* t;
    t = xc_a; xc_a = xc_n; xc_n = t;
    t = xt_a; xt_a = xt_n; xt_n = t;
    unsigned short* th;
    th = xch_a; xch_a = xch_n; xch_n = th;
    th = xth_a; xth_a = xth_n; xth_n = th;
  }

  // final node: output head
  head_kernel<<<dim3((N_C + 3) / 4), dim3(256), 0, stream>>>(xc_a, Wo1, bo1, Wo2, bo2, out, N_C);
}

// Round 12
// 597.476 us; speedup vs baseline: 1.0522x; 1.0522x over previous
//
#include <hip/hip_runtime.h>

typedef unsigned int uint32;
typedef __bf16 bf16x8 __attribute__((ext_vector_type(8)));
typedef __bf16 bf16x4 __attribute__((ext_vector_type(4)));
typedef float f32x4 __attribute__((ext_vector_type(4)));

constexpr int N_C = 100000, N_T = 5000, E_EDGES = 2000000;
constexpr int D_C = 1024, D_T = 1280, H = 64, H2 = 32, NL = 3;
constexpr int PJC = (N_C + 63) / 64;     // 1563 proj blocks (64 rows/block)
constexpr int PJT = (N_T + 63) / 64;     // 79
constexpr int NBC64 = (N_C + 63) / 64;   // 1563 layerC blocks

// ---- CSR build (two-level counting sort, zero atomic-with-return) ----
constexpr int CCH = 200;                  // chunks per graph
constexpr int CHE = E_EDGES / CCH;        // 10000 edges per chunk (exact)
constexpr int SH_T = 4,  FB_T = 16;       // target: bucket = dst>>4, 16 fine bins
constexpr int SH_C = 8,  FB_C = 256;      // compound: bucket = dst>>8, 256 fine bins
constexpr int NB_T_B = (N_T + FB_T - 1) / FB_T;   // 313 buckets
constexpr int NB_C_B = (N_C + FB_C - 1) / FB_C;   // 391 buckets
constexpr int NB_TOT = NB_T_B + NB_C_B;           // 704
// packT entry: (dst<<SB)|src ; col output stores plain src
constexpr int PB_T = 17; constexpr uint32 PM_T = 0x1FFFFu;
constexpr int PB_C = 13; constexpr uint32 PM_C = 0x1FFFu;

__device__ inline unsigned short f2bf(float f) {
  uint32 u = __float_as_uint(f);
  u += 0x7fffu + ((u >> 16) & 1u);          // round-to-nearest-even
  return (unsigned short)(u >> 16);
}

// ---------------- prep: fragment-major weight packs + small transposes + zero totals
// Wf layout: Wf[frag*512 + l*8 + j] = W[(k0 + lk*8 + j)*64 + fn*16 + lm]
//   frag = (k0/32)*4 + fn, l = (lm | lk<<4)  -> bv loads are 64x16B contiguous
__global__ __launch_bounds__(256) void prep_kernel(
    const float* __restrict__ Wc, const float* __restrict__ Wt,
    const float* __restrict__ Wl, const float* __restrict__ Wr,
    __bf16* __restrict__ WfC, __bf16* __restrict__ WfT, __bf16* __restrict__ WsT,
    int* __restrict__ T)
{
  int t = blockIdx.x * 256 + threadIdx.x;
  const int Z = NB_TOT;
  const int A = D_C * 64;
  const int B = D_T * 64;
  const int S = 6 * 64 * 64;
  if (t < Z) { T[t] = 0; return; }
  t -= Z;
  if (t < A) {
    int j = t & 7, l = (t >> 3) & 63, frag = t >> 9;
    int k0 = (frag >> 2) * 32, fn = frag & 3;
    int lm = l & 15, lk = l >> 4;
    WfC[t] = (__bf16)Wc[(size_t)(k0 + lk * 8 + j) * 64 + fn * 16 + lm];
    return;
  }
  t -= A;
  if (t < B) {
    int j = t & 7, l = (t >> 3) & 63, frag = t >> 9;
    int k0 = (frag >> 2) * 32, fn = frag & 3;
    int lm = l & 15, lk = l >> 4;
    WfT[t] = (__bf16)Wt[(size_t)(k0 + lk * 8 + j) * 64 + fn * 16 + lm];
    return;
  }
  t -= B;
  if (t < S) {
    int i = t >> 12;
    int r = t & 4095; int n = r & 63, k = r >> 6;
    const float* src = (i < 3) ? (Wl + (size_t)i * 4096) : (Wr + (size_t)(i - 3) * 4096);
    WsT[(size_t)i * 4096 + (size_t)n * 64 + k] = (__bf16)src[(size_t)k * 64 + n];
  }
}

// ---------------- MFMA projection: LDS-staged contiguous streaming
// block = 256 thr, 64 rows; K-tile = 128 floats; LDS [64][152] bf16 (304B stride)
template<int K>
__device__ __forceinline__ void projLDS_body(
    const float* __restrict__ x, const __bf16* __restrict__ Wf,
    const float* __restrict__ b, float* __restrict__ y,
    unsigned short* __restrict__ yh, int n, int bidx)
{
  constexpr int NT = K / 128;
  constexpr int ST = 152;                  // LDS row stride in bf16 (19.5 KB total)
  __shared__ __align__(16) __bf16 sA[64 * ST];

  int t = threadIdx.x;
  int w = t >> 6, l = t & 63;
  int lm = l & 15, lk = l >> 4;
  int bbase = bidx * 64;
  int rowbase = bbase + w * 16;

  f32x4 acc[4] = {{0,0,0,0},{0,0,0,0},{0,0,0,0},{0,0,0,0}};

  // staging map: idx = r*256+t; row = idx>>5, c4 = idx&31 (32 float4 per 128-f row)
  int srow = t >> 5;                       // rounds advance row by 8
  int sc4  = t & 31;

  for (int tile = 0; tile < NT; ++tile) {
    if (tile) __syncthreads();             // previous tile's reads complete
    float4 g[8];
#pragma unroll
    for (int r = 0; r < 8; ++r) {
      int row = srow + r * 8;
      int gr = bbase + row; if (gr >= n) gr = n - 1;
      g[r] = *(const float4*)(x + (size_t)gr * K + tile * 128 + sc4 * 4);
    }
#pragma unroll
    for (int r = 0; r < 8; ++r) {
      int row = srow + r * 8;
      bf16x4 v;
      v[0] = (__bf16)g[r].x; v[1] = (__bf16)g[r].y;
      v[2] = (__bf16)g[r].z; v[3] = (__bf16)g[r].w;
      *(bf16x4*)(sA + (size_t)row * ST + sc4 * 4) = v;
    }
    __syncthreads();

#pragma unroll
    for (int kk = 0; kk < 4; ++kk) {
      bf16x8 a0 = *(const bf16x8*)(sA + (size_t)(w * 16 + lm) * ST + kk * 32 + lk * 8);
#pragma unroll
      for (int fn = 0; fn < 4; ++fn) {
        bf16x8 bv = *(const bf16x8*)(Wf + ((size_t)(tile * 4 + kk) * 4 + fn) * 512 + l * 8);
        acc[fn] = __builtin_amdgcn_mfma_f32_16x16x32_bf16(a0, bv, acc[fn], 0, 0, 0);
      }
    }
  }

#pragma unroll
  for (int fn = 0; fn < 4; ++fn) {
    int col = fn * 16 + lm;
    float bb = b[col];
#pragma unroll
    for (int reg = 0; reg < 4; ++reg) {
      int row = rowbase + lk * 4 + reg;
      if (row < n) {
        float o = fmaxf(acc[fn][reg] + bb, 0.f);
        y[(size_t)row * 64 + col] = o;
        yh[(size_t)row * 64 + col] = f2bf(o);
      }
    }
  }
}

__global__ __launch_bounds__(256) void proj_kernel(
    const float* __restrict__ x_comp, const __bf16* __restrict__ WfC,
    const float* __restrict__ bc, float* __restrict__ xc, unsigned short* __restrict__ xch,
    const float* __restrict__ x_tgt, const __bf16* __restrict__ WfT,
    const float* __restrict__ bt, float* __restrict__ xt, unsigned short* __restrict__ xth)
{
  if (blockIdx.x < PJC) projLDS_body<D_C>(x_comp, WfC, bc, xc, xch, N_C, blockIdx.x);
  else                  projLDS_body<D_T>(x_tgt, WfT, bt, xt, xth, N_T, blockIdx.x - PJC);
}

// ---------------- csr1: per-chunk coarse-bucket histograms (LDS)
__global__ __launch_bounds__(256) void csr1_kernel(
    const int* __restrict__ dst_ct, const int* __restrict__ dst_tc,
    int* __restrict__ h1, int* __restrict__ T)
{
  __shared__ int hist[NB_C_B];
  int graph = (blockIdx.x >= CCH) ? 1 : 0;
  int chunk = graph ? (blockIdx.x - CCH) : blockIdx.x;
  const int* dst = graph ? dst_tc : dst_ct;
  int NB = graph ? NB_C_B : NB_T_B;
  int SH = graph ? SH_C : SH_T;
  for (int i = threadIdx.x; i < NB; i += 256) hist[i] = 0;
  __syncthreads();
  int e0 = chunk * CHE;
  for (int i = threadIdx.x; i < CHE; i += 256)
    atomicAdd(&hist[dst[e0 + i] >> SH], 1);
  __syncthreads();
  int* h1g = h1 + (graph ? (size_t)NB_T_B * CCH : 0);
  int* Tg  = T + (graph ? NB_T_B : 0);
  for (int i = threadIdx.x; i < NB; i += 256) {
    int v = hist[i];
    h1g[(size_t)i * CCH + chunk] = v;
    if (v) atomicAdd(&Tg[i], v);       // fire-and-forget
  }
}

// ---------------- csr2: per-bucket bases + chunk-prefix of h1 row
__global__ __launch_bounds__(256) void csr2_kernel(
    const int* __restrict__ h1, const int* __restrict__ T, int* __restrict__ b1)
{
  __shared__ int sh[256];
  __shared__ int loc2[512];
  int b = blockIdx.x;
  int graph = (b >= NB_T_B) ? 1 : 0;
  int nb = graph ? NB_C_B : NB_T_B;
  int base = graph ? NB_T_B : 0;
  int bl = b - base;
  int tid = threadIdx.x;
  int v0 = (2 * tid     < nb) ? T[base + 2 * tid]     : 0;
  int v1 = (2 * tid + 1 < nb) ? T[base + 2 * tid + 1] : 0;
  int t = v0 + v1;
  sh[tid] = t;
  __syncthreads();
  for (int off = 1; off < 256; off <<= 1) {
    int xv = (tid >= off) ? sh[tid - off] : 0;
    __syncthreads(); sh[tid] += xv; __syncthreads();
  }
  int excl = sh[tid] - t;
  loc2[2 * tid] = excl;
  loc2[2 * tid + 1] = excl + v0;
  __syncthreads();
  int B = loc2[bl];
  const int* row = h1 + (graph ? (size_t)NB_T_B * CCH : 0) + (size_t)bl * CCH;
  int hv = (tid < CCH) ? row[tid] : 0;
  sh[tid] = hv;
  __syncthreads();
  for (int off = 1; off < 256; off <<= 1) {
    int xv = (tid >= off) ? sh[tid - off] : 0;
    __syncthreads(); sh[tid] += xv; __syncthreads();
  }
  int e2 = sh[tid] - hv;
  if (tid < CCH) {
    int* b1g = b1 + (graph ? (size_t)NB_T_B * CCH : 0) + (size_t)bl * CCH;
    b1g[tid] = B + e2;
  }
}

// ---------------- csr3: scatter edges into bucket-major temp (packed)
__global__ __launch_bounds__(256) void csr3_kernel(
    const int* __restrict__ src_ct, const int* __restrict__ dst_ct,
    const int* __restrict__ src_tc, const int* __restrict__ dst_tc,
    const int* __restrict__ b1, uint32* __restrict__ packT_t, uint32* __restrict__ packT_c)
{
  __shared__ int cur[NB_C_B];
  int graph = (blockIdx.x >= CCH) ? 1 : 0;
  int chunk = graph ? (blockIdx.x - CCH) : blockIdx.x;
  const int* dst = graph ? dst_tc : dst_ct;
  const int* src = graph ? src_tc : src_ct;
  uint32* packT = graph ? packT_c : packT_t;
  int NB = graph ? NB_C_B : NB_T_B;
  int SH = graph ? SH_C : SH_T;
  int SB = graph ? PB_C : PB_T;
  const int* b1g = b1 + (graph ? (size_t)NB_T_B * CCH : 0);
  for (int i = threadIdx.x; i < NB; i += 256) cur[i] = b1g[(size_t)i * CCH + chunk];
  __syncthreads();
  int e0 = chunk * CHE;
  for (int i = threadIdx.x; i < CHE; i += 256) {
    int d = dst[e0 + i], s = src[e0 + i];
    int p = atomicAdd(&cur[d >> SH], 1);   // LDS atomic
    packT[p] = ((uint32)d << SB) | (uint32)s;
  }
}

// ---------------- csr4: per-bucket fine counting sort -> rowptr + col (plain src)
__global__ __launch_bounds__(256) void csr4_kernel(
    const int* __restrict__ b1, const uint32* __restrict__ packT_t,
    const uint32* __restrict__ packT_c,
    int* __restrict__ rowptr_t, int* __restrict__ col_ct,
    int* __restrict__ rowptr_c, int* __restrict__ col_tc)
{
  __shared__ int hist[FB_C];
  __shared__ int exc[256];
  int b = blockIdx.x;
  int graph = (b >= NB_T_B) ? 1 : 0;
  int bl = graph ? (b - NB_T_B) : b;
  int nb = graph ? NB_C_B : NB_T_B;
  int FB = graph ? FB_C : FB_T;
  int SB = graph ? PB_C : PB_T;
  uint32 SM = graph ? PM_C : PM_T;
  uint32 FMM = (uint32)(FB - 1);
  int N  = graph ? N_C : N_T;
  const uint32* packT = graph ? packT_c : packT_t;
  int* rowptr = graph ? rowptr_c : rowptr_t;
  int* col    = graph ? col_tc : col_ct;
  const int* b1g = b1 + (graph ? (size_t)NB_T_B * CCH : 0);
  int seg0 = b1g[(size_t)bl * CCH];
  int seg1 = (bl + 1 < nb) ? b1g[(size_t)(bl + 1) * CCH] : E_EDGES;
  int tid = threadIdx.x;
  if (tid < FB) hist[tid] = 0;
  __syncthreads();
  for (int i = seg0 + tid; i < seg1; i += 256)
    atomicAdd(&hist[(packT[i] >> SB) & FMM], 1);
  __syncthreads();
  int hv = (tid < FB) ? hist[tid] : 0;
  exc[tid] = hv;
  __syncthreads();
  for (int off = 1; off < 256; off <<= 1) {
    int xv = (tid >= off) ? exc[tid - off] : 0;
    __syncthreads(); exc[tid] += xv; __syncthreads();
  }
  int excl = exc[tid] - hv;
  __syncthreads();
  if (tid < FB) {
    int gbin = bl * FB + tid;
    if (gbin <= N) rowptr[gbin] = seg0 + excl;
    hist[tid] = seg0 + excl;
  }
  __syncthreads();
  for (int i = seg0 + tid; i < seg1; i += 256) {
    uint32 pk = packT[i];
    int p = atomicAdd(&hist[(pk >> SB) & FMM], 1);
    col[p] = (int)(pk & SM);                      // plain src index
  }
}

// ---------------- layerT: target-side SAGE, one block per row (masked batch gather)
__global__ __launch_bounds__(256) void layerT_kernel(
    const unsigned short* __restrict__ xch_a, const float* __restrict__ xt_a,
    const int* __restrict__ rowptr_t, const int* __restrict__ col_ct,
    const float* __restrict__ Wl_t, const float* __restrict__ bl_t, const float* __restrict__ Wr_t,
    float* __restrict__ xt_n, unsigned short* __restrict__ xth_n)
{
  __shared__ __align__(16) float part[4][64];
  __shared__ __align__(16) float opart[4][64];

  int l = threadIdx.x & 63, w = threadIdx.x >> 6;
  int d = l & 31, half = l >> 5;

  int r = blockIdx.x;
  int start = rowptr_t[r], end = rowptr_t[r + 1];
  int deg = end - start;
  int quarter = (deg + 3) >> 2;
  int js = start + w * quarter;
  int je = js + quarter; if (je > end) je = end;
  const uint32* xp = (const uint32*)xch_a;
  float a0 = 0.f, a1 = 0.f;
  int j0 = js + half;
  for (int j = j0; j < je; j += 16) {      // 8 masked edges per half per batch
    int idx[8]; uint32 vv[8];
#pragma unroll
    for (int k = 0; k < 8; ++k) {
      int jj = j + 2 * k;
      idx[k] = col_ct[(jj < je) ? jj : j];
    }
#pragma unroll
    for (int k = 0; k < 8; ++k) vv[k] = xp[(size_t)idx[k] * 32 + d];
#pragma unroll
    for (int k = 0; k < 8; ++k) {
      bool m = (j + 2 * k) < je;
      a0 += m ? __uint_as_float(vv[k] << 16) : 0.f;
      a1 += m ? __uint_as_float(vv[k] & 0xffff0000u) : 0.f;
    }
  }
  a0 += __shfl_xor(a0, 32, 64);
  a1 += __shfl_xor(a1, 32, 64);
  if (half == 0) *(float2*)&part[w][2 * d] = make_float2(a0, a1);
  __syncthreads();
  float m = (part[0][l] + part[1][l] + part[2][l] + part[3][l])
            * ((deg > 0) ? (1.0f / (float)deg) : 0.f);
  float xv = xt_a[(size_t)r * 64 + l];
  float o = 0.f;
  int k0 = w * 16;
#pragma unroll
  for (int kk = 0; kk < 16; ++kk) {
    int k = k0 + kk;
    float mk = __uint_as_float(__builtin_amdgcn_readlane(__float_as_uint(m), k));
    float xk = __uint_as_float(__builtin_amdgcn_readlane(__float_as_uint(xv), k));
    o = fmaf(mk, Wl_t[k * 64 + l], o);
    o = fmaf(xk, Wr_t[k * 64 + l], o);
  }
  opart[w][l] = o;
  __syncthreads();
  if (w == 0) {
    float oo = opart[0][l] + opart[1][l] + opart[2][l] + opart[3][l] + bl_t[l];
    float res = fmaxf(oo, 0.f) + xv;
    xt_n[(size_t)r * 64 + l] = res;
    xth_n[(size_t)r * 64 + l] = f2bf(res);
  }
}

// ---------------- layerC: 64 rows/block (16/wave) reg-acc agg + MFMA combine
__global__ __launch_bounds__(256) void layerC_kernel(
    const unsigned short* __restrict__ xch_a,
    const unsigned short* __restrict__ xth_a, const int* __restrict__ rowptr_c,
    const int* __restrict__ col_tc,
    const __bf16* __restrict__ WlT, const __bf16* __restrict__ WrT,
    const float* __restrict__ bl_c, const float* __restrict__ xc_a,
    float* __restrict__ xc_n, unsigned short* __restrict__ xch_n)
{
  __shared__ __align__(16) uint32 smem_u[64 * 36];   // 9.2 KB packed bf16 means

  int l = threadIdx.x & 63, w = threadIdx.x >> 6;
  int d = l & 31, half = l >> 5;

  int bbase = blockIdx.x * 64;

  int rp_idx = bbase + w * 16 + ((l <= 16) ? l : 16);
  if (rp_idx > N_C) rp_idx = N_C;
  int rpl = rowptr_c[rp_idx];
  const uint32* xp = (const uint32*)xth_a;

#pragma unroll 1
  for (int t = 0; t < 8; ++t) {
    int s = __shfl(rpl, 2 * t + half, 64);
    int e = __shfl(rpl, 2 * t + half + 1, 64);
    float a0 = 0.f, a1 = 0.f;
    int n = e - s;
    for (int j = 0; j < n; j += 8) {       // masked batch of 8, no serial tail
      int idx[8]; uint32 vv[8];
#pragma unroll
      for (int k = 0; k < 8; ++k) {
        int jj = s + j + k;
        idx[k] = col_tc[(jj < e) ? jj : s];
      }
#pragma unroll
      for (int k = 0; k < 8; ++k) vv[k] = xp[(size_t)idx[k] * 32 + d];
#pragma unroll
      for (int k = 0; k < 8; ++k) {
        bool m = (j + k) < n;
        a0 += m ? __uint_as_float(vv[k] << 16) : 0.f;
        a1 += m ? __uint_as_float(vv[k] & 0xffff0000u) : 0.f;
      }
    }
    float inv = (n > 0) ? (1.0f / (float)n) : 0.f;
    uint32 packed = (uint32)f2bf(a0 * inv) | ((uint32)f2bf(a1 * inv) << 16);
    smem_u[(size_t)(w * 16 + 2 * t + half) * 36 + d] = packed;
  }
  __syncthreads();

  // MFMA combine: xnew = relu(mean@Wl + X@Wr + bl) + X   (16 rows/wave)
  int lm = l & 15, lk = l >> 4;
  int base = bbase + w * 16;
  int r0 = base + lm; if (r0 >= N_C) r0 = N_C - 1;
  const unsigned short* x0 = xch_a + (size_t)r0 * 64 + lk * 8;
  const __bf16* wl = WlT + (size_t)lm * 64 + lk * 8;
  const __bf16* wr = WrT + (size_t)lm * 64 + lk * 8;

  f32x4 acc[4] = {{0,0,0,0},{0,0,0,0},{0,0,0,0},{0,0,0,0}};

#pragma unroll
  for (int ks = 0; ks < 64; ks += 32) {
    bf16x8 am0 = *(const bf16x8*)&smem_u[(size_t)(w * 16 + lm) * 36 + lk * 4 + (ks >> 1)];
    bf16x8 ax0 = *(const bf16x8*)(x0 + ks);
#pragma unroll
    for (int fn = 0; fn < 4; ++fn) {
      bf16x8 bl_v = *(const bf16x8*)(wl + (size_t)fn * 16 * 64 + ks);
      bf16x8 br_v = *(const bf16x8*)(wr + (size_t)fn * 16 * 64 + ks);
      acc[fn] = __builtin_amdgcn_mfma_f32_16x16x32_bf16(am0, bl_v, acc[fn], 0, 0, 0);
      acc[fn] = __builtin_amdgcn_mfma_f32_16x16x32_bf16(ax0, br_v, acc[fn], 0, 0, 0);
    }
  }

#pragma unroll
  for (int fn = 0; fn < 4; ++fn) {
    int col = fn * 16 + lm;
    float bb = bl_c[col];
#pragma unroll
    for (int reg = 0; reg < 4; ++reg) {
      int row = base + lk * 4 + reg;
      if (row < N_C) {
        float xv = xc_a[(size_t)row * 64 + col];
        float o = fmaxf(acc[fn][reg] + bb, 0.f) + xv;
        xc_n[(size_t)row * 64 + col] = o;
        xch_n[(size_t)row * 64 + col] = f2bf(o);
      }
    }
  }
}

// ---------------- head: out[r] = relu(xc[r] @ Wo1 + bo1) @ Wo2 + bo2
__global__ __launch_bounds__(256) void head_kernel(
    const float* __restrict__ xc, const float* __restrict__ Wo1,
    const float* __restrict__ bo1, const float* __restrict__ Wo2,
    const float* __restrict__ bo2, float* __restrict__ out, int n)
{
  int lane = threadIdx.x & 63;
  int wid = blockIdx.x * (blockDim.x >> 6) + (threadIdx.x >> 6);
  if (wid >= n) return;
  float xv = xc[(size_t)wid * 64 + lane];
  float h = (lane < H2) ? bo1[lane] : 0.f;
  const float* wcol = Wo1 + ((lane < H2) ? lane : 0);
#pragma unroll 8
  for (int k = 0; k < 64; ++k) {
    float xk = __uint_as_float(__builtin_amdgcn_readlane(__float_as_uint(xv), k));
    h = fmaf(xk, wcol[k * H2], h);
  }
  float v = (lane < H2) ? fmaxf(h, 0.f) * Wo2[lane] : 0.f;
#pragma unroll
  for (int off = 32; off > 0; off >>= 1) v += __shfl_down(v, off, 64);
  if (lane == 0) out[wid] = v + bo2[0];
}

extern "C" void kernel_launch(void* const* d_in, const int* in_sizes, int n_in,
                              void* d_out, int out_size, void* d_ws, size_t ws_size,
                              hipStream_t stream)
{
  const float* x_comp = (const float*)d_in[0];
  const float* x_tgt  = (const float*)d_in[1];
  const int*   src_ct = (const int*)d_in[2];
  const int*   dst_ct = (const int*)d_in[3];
  const int*   src_tc = (const int*)d_in[4];
  const int*   dst_tc = (const int*)d_in[5];
  const float* Wc    = (const float*)d_in[6];
  const float* bc    = (const float*)d_in[7];
  const float* Wt    = (const float*)d_in[8];
  const float* bt    = (const float*)d_in[9];
  const float* Wl_ct = (const float*)d_in[10];
  const float* bl_ct = (const float*)d_in[11];
  const float* Wr_ct = (const float*)d_in[12];
  const float* Wl_tc = (const float*)d_in[13];
  const float* bl_tc = (const float*)d_in[14];
  const float* Wr_tc = (const float*)d_in[15];
  const float* Wo1   = (const float*)d_in[16];
  const float* bo1   = (const float*)d_in[17];
  const float* Wo2   = (const float*)d_in[18];
  const float* bo2   = (const float*)d_in[19];
  float* out = (float*)d_out;

  char* p = (char*)d_ws;
  auto alloc = [&](size_t bytes) {
    char* q = p;
    p += (bytes + 255) & ~(size_t)255;
    return q;
  };
  float* xc   = (float*)alloc((size_t)N_C * H * 4);
  float* xt   = (float*)alloc((size_t)N_T * H * 4);
  float* xc_b = (float*)alloc((size_t)N_C * H * 4);
  float* xt_b = (float*)alloc((size_t)N_T * H * 4);
  unsigned short* xch   = (unsigned short*)alloc((size_t)N_C * H * 2);
  unsigned short* xth   = (unsigned short*)alloc((size_t)N_T * H * 2);
  unsigned short* xch_b = (unsigned short*)alloc((size_t)N_C * H * 2);
  unsigned short* xth_b = (unsigned short*)alloc((size_t)N_T * H * 2);
  __bf16* WfC = (__bf16*)alloc((size_t)D_C * H * 2);
  __bf16* WfT = (__bf16*)alloc((size_t)D_T * H * 2);
  __bf16* WsT = (__bf16*)alloc((size_t)6 * H * H * 2);
  int*    h1        = (int*)alloc((size_t)NB_TOT * CCH * 4);
  int*    b1        = (int*)alloc((size_t)NB_TOT * CCH * 4);
  int*    T         = (int*)alloc((size_t)NB_TOT * 4);
  uint32* packT_t   = (uint32*)alloc((size_t)E_EDGES * 4);
  uint32* packT_c   = (uint32*)alloc((size_t)E_EDGES * 4);
  int*    rowptr_t  = (int*)alloc((size_t)(N_T + 1) * 4);
  int*    rowptr_c  = (int*)alloc((size_t)(N_C + 1) * 4);
  int*    col_ct    = (int*)alloc((size_t)E_EDGES * 4);
  int*    col_tc    = (int*)alloc((size_t)E_EDGES * 4);

  // node 1: weight prep (fragment-major packs) + zero bucket totals
  const int PREP_TOTAL = NB_TOT + D_C * 64 + D_T * 64 + 6 * 4096;
  prep_kernel<<<dim3((PREP_TOTAL + 255) / 256), dim3(256), 0, stream>>>(
      Wc, Wt, Wl_tc, Wr_tc, WfC, WfT, WsT, T);

  // node 2: both dense input projections (LDS-staged contiguous streaming)
  proj_kernel<<<dim3(PJC + PJT), dim3(256), 0, stream>>>(
      x_comp, WfC, bc, xc, xch, x_tgt, WfT, bt, xt, xth);

  // nodes 3-6: CSR build (two-level counting sort)
  csr1_kernel<<<dim3(2 * CCH), dim3(256), 0, stream>>>(dst_ct, dst_tc, h1, T);
  csr2_kernel<<<dim3(NB_TOT), dim3(256), 0, stream>>>(h1, T, b1);
  csr3_kernel<<<dim3(2 * CCH), dim3(256), 0, stream>>>(
      src_ct, dst_ct, src_tc, dst_tc, b1, packT_t, packT_c);
  csr4_kernel<<<dim3(NB_TOT), dim3(256), 0, stream>>>(
      b1, packT_t, packT_c, rowptr_t, col_ct, rowptr_c, col_tc);

  // layers: 2 nodes per layer (layerT then layerC)
  float* xc_a = xc; float* xt_a = xt;
  float* xc_n = xc_b; float* xt_n = xt_b;
  unsigned short* xch_a = xch; unsigned short* xth_a = xth;
  unsigned short* xch_n = xch_b; unsigned short* xth_n = xth_b;
  for (int l = 0; l < NL; ++l) {
    layerT_kernel<<<dim3(N_T), dim3(256), 0, stream>>>(
        xch_a, xt_a, rowptr_t, col_ct,
        Wl_ct + (size_t)l * H * H, bl_ct + (size_t)l * H, Wr_ct + (size_t)l * H * H,
        xt_n, xth_n);
    layerC_kernel<<<dim3(NBC64), dim3(256), 0, stream>>>(
        xch_a, xth_a, rowptr_c, col_tc,
        WsT + (size_t)l * H * H, WsT + (size_t)(3 + l) * H * H,
        bl_tc + (size_t)l * H, xc_a, xc_n, xch_n);
    float* t;
    t = xc_a; xc_a = xc_n; xc_n = t;
    t = xt_a; xt_a = xt_n; xt_n = t;
    unsigned short* th;
    th = xch_a; xch_a = xch_n; xch_n = th;
    th = xth_a; xth_a = xth_n; xth_n = th;
  }

  // final node: output head
  head_kernel<<<dim3((N_C + 3) / 4), dim3(256), 0, stream>>>(xc_a, Wo1, bo1, Wo2, bo2, out, N_C);
}